// Round 7
// baseline (391.220 us; speedup 1.0000x reference)
//
#include <hip/hip_runtime.h>

#define Bn 32
#define Cc 128
#define Nn 307
#define Ll 12
#define LH 13
#define LAYERS 4
#define BN_EPS 1e-5f
#define SCW (Cc + 1)  // padded LDS stride

#define NT 64      // n-tile size
#define NTILES 5   // ceil(307/64)
#define CK 4       // c per chunk
#define TS 13      // LDS tile stride over t (12 data + 1 pad -> conflict-free)

// ---- fused single-pass: block per (ch,b,ntile). One coalesced float4 read of X.
// G1[(ch*4+l)*Bn+b][t0][n] accumulated in regs; G2 partials per n-tile -> G2p.
__global__ __launch_bounds__(256) void k_g12(const float* __restrict__ XL,
                                             const float* __restrict__ XH,
                                             const float* __restrict__ lc1,
                                             const float* __restrict__ hc1,
                                             const float* __restrict__ lc2,
                                             const float* __restrict__ hc2,
                                             float* __restrict__ G1,
                                             float* __restrict__ G2p) {
    __shared__ float tile[CK * NT * TS];   // 13.3 KB
    __shared__ float s_c1[LAYERS * Cc];
    __shared__ float s_c2[LAYERS * Nn];
    __shared__ float s_red[208 * 4];       // (52 pos x 4 quarters) x 4 layers
    int blk = blockIdx.x;
    int ntile = blk % NTILES;
    int b = (blk / NTILES) % Bn;
    int ch = blk / (NTILES * Bn);
    const float* X = ch ? XH : XL;
    const float* c1 = ch ? hc1 : lc1;
    const float* c2 = ch ? hc2 : lc2;
    const int T = ch ? LH : Ll;
    const int pad = ch ? 1 : 0;
    int n0 = ntile * NT;
    int ncnt = min(NT, Nn - n0);
    int tid = threadIdx.x;
    for (int j = tid; j < LAYERS * Cc; j += 256) s_c1[j] = c1[j];
    for (int j = tid; j < LAYERS * Nn; j += 256) s_c2[j] = c2[j];

    float g1acc[4][LAYERS];
#pragma unroll
    for (int k = 0; k < 4; ++k)
#pragma unroll
        for (int l = 0; l < LAYERS; ++l) g1acc[k][l] = 0.f;

    const float* Xb = X + (size_t)b * Cc * Nn * Ll;
    int per = ncnt * 3;  // float4 per c-slab

    for (int c0 = 0; c0 < Cc; c0 += CK) {
        __syncthreads();
        // ---- coalesced tile load: CK slabs of ncnt*12 consecutive floats ----
        for (int j = tid; j < CK * per; j += 256) {
            int ci = j / per, j4 = j - ci * per;
            float4 vv = *(const float4*)(Xb + ((size_t)(c0 + ci) * Nn + n0) * Ll + j4 * 4);
            int flat = j4 * 4;
            int nn = flat / 12, tt = flat - nn * 12;
            float* dst = &tile[(ci * NT + nn) * TS + tt];
            dst[0] = vv.x; dst[1] = vv.y; dst[2] = vv.z; dst[3] = vv.w;
        }
        __syncthreads();
        // ---- G1 accumulate (regs), pos p = nloc*13 + t0 ----
#pragma unroll
        for (int k = 0; k < 4; ++k) {
            int p = tid + k * 256;
            if (p < NT * 13) {
                int nloc = p / 13, t0 = p - nloc * 13, tsrc = t0 - pad;
                if (nloc < ncnt && tsrc >= 0 && t0 < T) {
                    float x0 = tile[(0 * NT + nloc) * TS + tsrc];
                    float x1 = tile[(1 * NT + nloc) * TS + tsrc];
                    float x2 = tile[(2 * NT + nloc) * TS + tsrc];
                    float x3 = tile[(3 * NT + nloc) * TS + tsrc];
#pragma unroll
                    for (int l = 0; l < LAYERS; ++l) {
                        g1acc[k][l] += x0 * s_c1[l * Cc + c0] + x1 * s_c1[l * Cc + c0 + 1]
                                     + x2 * s_c1[l * Cc + c0 + 2] + x3 * s_c1[l * Cc + c0 + 3];
                    }
                }
            }
        }
        // ---- G2 partials: pos = ci*13+t0 (52), 4 n-quarters ----
        if (tid < 208) {
            int pos = tid >> 2, q = tid & 3;
            int ci = pos / 13, t0 = pos - ci * 13, tsrc = t0 - pad;
            float s0 = 0.f, s1 = 0.f, s2 = 0.f, s3 = 0.f;
            if (tsrc >= 0 && t0 < T) {
                int nlo = q * 16, nhi = min(nlo + 16, ncnt);
                for (int n = nlo; n < nhi; ++n) {
                    float xv = tile[(ci * NT + n) * TS + tsrc];
                    int ng = n0 + n;
                    s0 += xv * s_c2[0 * Nn + ng];
                    s1 += xv * s_c2[1 * Nn + ng];
                    s2 += xv * s_c2[2 * Nn + ng];
                    s3 += xv * s_c2[3 * Nn + ng];
                }
            }
            float* rr = &s_red[tid * 4];
            rr[0] = s0; rr[1] = s1; rr[2] = s2; rr[3] = s3;
        }
        __syncthreads();
        if (tid < 52) {
            int ci = tid / 13, t0 = tid - ci * 13;
            int c = c0 + ci;
#pragma unroll
            for (int l = 0; l < LAYERS; ++l) {
                float v = s_red[(tid * 4 + 0) * 4 + l] + s_red[(tid * 4 + 1) * 4 + l]
                        + s_red[(tid * 4 + 2) * 4 + l] + s_red[(tid * 4 + 3) * 4 + l];
                G2p[((((size_t)(ch * LAYERS + l) * Bn + b) * NTILES + ntile) * LH + t0) * Cc + c] = v;
            }
        }
    }
    // ---- write G1 (zero rows preserved: high t0=0 stays 0) ----
#pragma unroll
    for (int k = 0; k < 4; ++k) {
        int p = tid + k * 256;
        if (p < NT * 13) {
            int nloc = p / 13, t0 = p - nloc * 13;
            if (nloc < ncnt && t0 < T) {
#pragma unroll
                for (int l = 0; l < LAYERS; ++l)
                    G1[((size_t)(ch * LAYERS + l) * Bn + b) * (LH * Nn) + t0 * Nn + n0 + nloc] =
                        g1acc[k][l];
            }
        }
    }
}

// ---- per (ch,l,b): GW = G1*w, then M[t0][t1] = sum_c GW*G2 -> global ----
__global__ __launch_bounds__(256) void k_gwm(const float* __restrict__ lw,
                                             const float* __restrict__ hw,
                                             const float* __restrict__ G1,
                                             const float* __restrict__ G2p,
                                             float* __restrict__ M) {
    __shared__ float sG1[LH * Nn];
    __shared__ float sAcc[2][LH * SCW];
    __shared__ float sG2[LH * SCW];
    int blk = blockIdx.x;  // (ch*LAYERS + l)*Bn + b
    int cl = blk / Bn;
    int l = cl % LAYERS;
    int ch = cl / LAYERS;
    int T = ch ? LH : Ll;
    const float* w = (ch ? hw : lw) + (size_t)l * Nn * Cc;
    const float* g1 = G1 + (size_t)blk * (LH * Nn);
    const float* g2 = G2p + (size_t)blk * (NTILES * LH * Cc);
    int tid = threadIdx.x;
    for (int i = tid; i < LH * Nn; i += 256) sG1[i] = (i < T * Nn) ? g1[i] : 0.f;
    for (int i = tid; i < T * Cc; i += 256) {
        int t0 = i / Cc, c = i % Cc;
        float a = 0.f;
#pragma unroll
        for (int tl = 0; tl < NTILES; ++tl) a += g2[((size_t)tl * LH + t0) * Cc + c];
        sG2[t0 * SCW + c] = a;
    }
    __syncthreads();
    int half = tid >> 7;
    int c = tid & 127;
    float acc[LH];
#pragma unroll
    for (int t = 0; t < LH; ++t) acc[t] = 0.f;
    int n0 = half ? (Nn / 2) : 0;
    int n1 = half ? Nn : (Nn / 2);
    for (int n = n0; n < n1; ++n) {
        float wv = w[(size_t)n * Cc + c];
#pragma unroll
        for (int t = 0; t < LH; ++t) acc[t] += sG1[t * Nn + n] * wv;
    }
#pragma unroll
    for (int t = 0; t < LH; ++t) sAcc[half][t * SCW + c] = acc[t];
    __syncthreads();
    for (int i = tid; i < LH * Cc; i += 256) {
        int t = i / Cc, cc = i % Cc;
        sAcc[0][t * SCW + cc] += sAcc[1][t * SCW + cc];
    }
    __syncthreads();
    float* Mo = M + (size_t)blk * (LH * LH);
    for (int i = tid; i < T * T; i += 256) {
        int t0 = i / T, t1 = i % T;
        float a = 0.f;
#pragma unroll
        for (int cc = 0; cc < Cc; ++cc) a += sAcc[0][t0 * SCW + cc] * sG2[t1 * SCW + cc];
        Mo[t0 * LH + t1] = a;
    }
}

// ---- 4-layer chain, compile-time T so all inner loops unroll & LDS reads batch ----
template <int T>
__device__ __forceinline__ void chain_impl(float* __restrict__ sbuf,
                                           float* __restrict__ sMean,
                                           float* __restrict__ sScale,
                                           float* __restrict__ sShift,
                                           const float* __restrict__ M,
                                           const float* __restrict__ bbp,
                                           const float* __restrict__ vp,
                                           const float* __restrict__ gp,
                                           const float* __restrict__ bep,
                                           float* __restrict__ Pcol, int ch) {
    const int TT = T * T;
    const int BUF = Bn * LH * LH;
    int tid = threadIdx.x;
    int ip = 0, ia = 1, ib = 2;
    for (int i = tid; i < Bn * TT; i += 1024) {
        int r = i % TT;
        sbuf[i] = (r / T == r % T) ? 1.f : 0.f;
    }
    __syncthreads();
    for (int l = 0; l < LAYERS; ++l) {
        float* P = sbuf + ip * BUF;
        float* X1 = sbuf + ia * BUF;
        float* X2 = sbuf + ib * BUF;
        const float* Ml = M + ((size_t)(ch * LAYERS + l) * Bn) * (LH * LH);
        const float* bbl = bbp + l * TT;
        const float* vl = vp + l * TT;
        for (int i = tid; i < Bn * LH * LH; i += 1024) X1[i] = Ml[i];
        __syncthreads();
        for (int i = tid; i < Bn * TT; i += 1024) {
            int b = i / TT, r = i % TT, t = r / T, t1 = r % T;
            const float* Pb = P + b * TT;
            const float* Mb = X1 + b * LH * LH;
            float a = 0.f;
#pragma unroll
            for (int t0 = 0; t0 < T; ++t0) a += Pb[t0 * T + t] * Mb[t0 * LH + t1];
            X2[i] = a;
        }
        __syncthreads();
        for (int i = tid; i < Bn * TT; i += 1024) {
            int b = i / TT, r = i % TT, t = r / T, q = r % T;
            const float* S1b = X2 + b * TT + t * T;
            const float* Pb = P + b * TT;
            float a = bbl[r];
#pragma unroll
            for (int t1 = 0; t1 < T; ++t1) a += S1b[t1] * Pb[t1 * T + q];
            X1[i] = 1.f / (1.f + expf(-a));
        }
        __syncthreads();
        for (int i = tid; i < Bn * TT; i += 1024) {
            int b = i / TT, r = i % TT, t = r / T, q = r % T;
            float a = 0.f;
#pragma unroll
            for (int k = 0; k < T; ++k) a += vl[t * T + k] * X1[b * TT + k * T + q];
            X2[i] = a;
        }
        __syncthreads();
        if (tid < T * Bn) {
            int b = tid % Bn, q = tid / Bn;
            float s = 0.f, ss = 0.f;
#pragma unroll
            for (int t = 0; t < T; ++t) {
                float x = X2[b * TT + t * T + q];
                s += x;
                ss += x * x;
            }
            X1[q * Bn + b] = s;
            X1[T * Bn + q * Bn + b] = ss;
        }
        __syncthreads();
        if (tid < T) {
            float s = 0.f, ss = 0.f;
#pragma unroll 8
            for (int b = 0; b < Bn; ++b) {
                s += X1[tid * Bn + b];
                ss += X1[T * Bn + tid * Bn + b];
            }
            float inv = 1.f / (float)(Bn * T);
            float m = s * inv;
            float var = ss * inv - m * m;
            sMean[tid] = m;
            sScale[tid] = rsqrtf(var + BN_EPS) * gp[l * T + tid];
            sShift[tid] = bep[l * T + tid];
        }
        __syncthreads();
        if (tid < Bn * T) {
            int b = tid / T, t = tid % T;
            float vals[T];
            float mx = -1e30f;
#pragma unroll
            for (int q = 0; q < T; ++q) {
                float x = (X2[b * TT + t * T + q] - sMean[q]) * sScale[q] + sShift[q];
                vals[q] = x;
                mx = fmaxf(mx, x);
            }
            float sm = 0.f;
#pragma unroll
            for (int q = 0; q < T; ++q) {
                vals[q] = expf(vals[q] - mx);
                sm += vals[q];
            }
            float inv = 1.f / sm;
#pragma unroll
            for (int q = 0; q < T; ++q) X1[b * TT + t * T + q] = vals[q] * inv;
        }
        __syncthreads();
        for (int i = tid; i < Bn * TT; i += 1024) {
            int b = i / TT, r = i % TT, t0 = r / T, q = r % T;
            const float* Pb = P + b * TT;
            const float* Cb = X1 + b * TT + q * T;
            float a = 0.f;
#pragma unroll
            for (int t = 0; t < T; ++t) a += Pb[t0 * T + t] * Cb[t];
            X2[i] = a;
        }
        __syncthreads();
        int tmp = ip; ip = ib; ib = tmp;
    }
    const float* Pf = sbuf + ip * BUF;
    for (int i = tid; i < Bn * T; i += 1024) {
        int b = i / T, t0 = i % T;
        Pcol[ch * Bn * LH + b * LH + t0] = Pf[b * TT + t0 * T + (T - 1)];
    }
}

__global__ __launch_bounds__(1024) void k_chain(const float* __restrict__ M,
                                                const float* __restrict__ lb,
                                                const float* __restrict__ lv,
                                                const float* __restrict__ lg,
                                                const float* __restrict__ lbe,
                                                const float* __restrict__ hb,
                                                const float* __restrict__ hv,
                                                const float* __restrict__ hg,
                                                const float* __restrict__ hbe,
                                                float* __restrict__ Pcol) {
    __shared__ float sbuf[3 * Bn * LH * LH];
    __shared__ float sMean[LH], sScale[LH], sShift[LH];
    int ch = blockIdx.x;
    if (ch == 0)
        chain_impl<Ll>(sbuf, sMean, sScale, sShift, M, lb, lv, lg, lbe, Pcol, 0);
    else
        chain_impl<LH>(sbuf, sMean, sScale, sShift, M, hb, hv, hg, hbe, Pcol, 1);
}

// ---- final: residuals + alpha blend, float4 loads ----
__global__ __launch_bounds__(256) void k_final(const float* __restrict__ XL,
                                               const float* __restrict__ XH,
                                               const float* __restrict__ Pcol,
                                               const float* __restrict__ alpha,
                                               float* __restrict__ out) {
    __shared__ float s_pl[Ll];
    __shared__ float s_ph[LH];
    int b = blockIdx.y;
    int tid = threadIdx.x;
    if (tid < Ll) s_pl[tid] = Pcol[b * LH + tid];
    if (tid < LH) s_ph[tid] = Pcol[Bn * LH + b * LH + tid];
    __syncthreads();
    int cn = blockIdx.x * blockDim.x + tid;
    if (cn >= Cc * Nn) return;
    size_t idx = (size_t)b * Cc * Nn + cn;
    const float4* pl4 = (const float4*)(XL + idx * Ll);
    const float4* ph4 = (const float4*)(XH + idx * Ll);
    float4 l0 = pl4[0], l1 = pl4[1], l2 = pl4[2];
    float4 h0 = ph4[0], h1 = ph4[1], h2 = ph4[2];
    float accL = l0.x * s_pl[0] + l0.y * s_pl[1] + l0.z * s_pl[2] + l0.w * s_pl[3]
               + l1.x * s_pl[4] + l1.y * s_pl[5] + l1.z * s_pl[6] + l1.w * s_pl[7]
               + l2.x * s_pl[8] + l2.y * s_pl[9] + l2.z * s_pl[10] + l2.w * s_pl[11];
    float accH = h0.x * s_ph[1] + h0.y * s_ph[2] + h0.z * s_ph[3] + h0.w * s_ph[4]
               + h1.x * s_ph[5] + h1.y * s_ph[6] + h1.z * s_ph[7] + h1.w * s_ph[8]
               + h2.x * s_ph[9] + h2.y * s_ph[10] + h2.z * s_ph[11] + h2.w * s_ph[12];
    float a = 1.f / (1.f + expf(-alpha[0]));
    float xl = l2.w + accL;
    float xh = h2.w + accH;
    out[idx] = a * xl + (1.f - a) * xh;
}

extern "C" void kernel_launch(void* const* d_in, const int* in_sizes, int n_in,
                              void* d_out, int out_size, void* d_ws, size_t ws_size,
                              hipStream_t stream) {
    const float* XL = (const float*)d_in[0];
    const float* XH = (const float*)d_in[1];
    const float* lc1 = (const float*)d_in[2];
    const float* lc2 = (const float*)d_in[3];
    const float* lw = (const float*)d_in[4];
    const float* lb = (const float*)d_in[5];
    const float* lv = (const float*)d_in[6];
    const float* lg = (const float*)d_in[7];
    const float* lbeta = (const float*)d_in[8];
    const float* hc1 = (const float*)d_in[9];
    const float* hc2 = (const float*)d_in[10];
    const float* hw = (const float*)d_in[11];
    const float* hb = (const float*)d_in[12];
    const float* hv = (const float*)d_in[13];
    const float* hg = (const float*)d_in[14];
    const float* hbeta = (const float*)d_in[15];
    const float* alpha = (const float*)d_in[16];
    float* out = (float*)d_out;

    float* ws = (float*)d_ws;
    float* G1 = ws;                                                 // 1,021,696 floats
    float* G2p = G1 + (size_t)2 * LAYERS * Bn * LH * Nn;            // 2,129,920 floats
    float* M = G2p + (size_t)2 * LAYERS * Bn * NTILES * LH * Cc;    // 43,264
    float* Pcol = M + (size_t)2 * LAYERS * Bn * LH * LH;            // 832
    // total ~12.8 MB

    k_g12<<<2 * Bn * NTILES, 256, 0, stream>>>(XL, XH, lc1, hc1, lc2, hc2, G1, G2p);
    k_gwm<<<2 * LAYERS * Bn, 256, 0, stream>>>(lw, hw, G1, G2p, M);
    k_chain<<<2, 1024, 0, stream>>>(M, lb, lv, lg, lbeta, hb, hv, hg, hbeta, Pcol);
    k_final<<<dim3((Cc * Nn + 255) / 256, Bn), 256, 0, stream>>>(XL, XH, Pcol, alpha, out);
}

// Round 8
// 349.143 us; speedup vs baseline: 1.1205x; 1.1205x over previous
//
#include <hip/hip_runtime.h>

#define Bn 32
#define Cc 128
#define Nn 307
#define Ll 12
#define LH 13
#define LAYERS 4
#define BN_EPS 1e-5f
#define SCW (Cc + 1)  // padded LDS stride

#define NCQ 4        // c-chunks (32 c each) for G1 partials
#define NTL 5        // n-tiles of 64
#define NBA 1280     // part A blocks: 2ch * 32b * NCQ * NTL
#define NBB 416      // part B blocks: 2*32*128*13 / 256

// ---- Part A: G1 partials, vectorized float4 along t, no LDS tile.
// Thread: (ch,b,cq,ntile | l = tid>>6, nl = tid&63). 12 reg accums (tsrc-indexed).
// G1p layout: [((ch*4+l)*Bn+b)][cq][13][Nn]
// ---- Part B: G2 direct (R6 style): thread per (ch,b,c,t0), scalar n-loop.
__global__ __launch_bounds__(256) void k_g12(const float* __restrict__ XL,
                                             const float* __restrict__ XH,
                                             const float* __restrict__ lc1,
                                             const float* __restrict__ hc1,
                                             const float* __restrict__ lc2,
                                             const float* __restrict__ hc2,
                                             float* __restrict__ G1p,
                                             float* __restrict__ G2) {
    __shared__ float s_c2[LAYERS * Nn];
    int blk = blockIdx.x;
    int tid = threadIdx.x;
    if (blk < NBA) {
        int ntile = blk % NTL;
        int cq = (blk / NTL) % NCQ;
        int b = (blk / (NTL * NCQ)) % Bn;
        int ch = blk / (NTL * NCQ * Bn);
        const float* X = ch ? XH : XL;
        const float* c1 = ch ? hc1 : lc1;
        int pad = ch ? 1 : 0;
        int l = tid >> 6;
        int n = ntile * 64 + (tid & 63);
        if (n >= Nn) return;
        const float* c1l = c1 + l * Cc + cq * 32;
        const float* Xb = X + ((size_t)b * Cc + cq * 32) * Nn * Ll + (size_t)n * Ll;
        float acc[12];
#pragma unroll
        for (int t = 0; t < 12; ++t) acc[t] = 0.f;
        for (int c = 0; c < 32; ++c) {
            const float* p = Xb + (size_t)c * Nn * Ll;
            float4 v0 = *(const float4*)(p);
            float4 v1 = *(const float4*)(p + 4);
            float4 v2 = *(const float4*)(p + 8);
            float cv = c1l[c];
            acc[0] += v0.x * cv;  acc[1] += v0.y * cv;
            acc[2] += v0.z * cv;  acc[3] += v0.w * cv;
            acc[4] += v1.x * cv;  acc[5] += v1.y * cv;
            acc[6] += v1.z * cv;  acc[7] += v1.w * cv;
            acc[8] += v2.x * cv;  acc[9] += v2.y * cv;
            acc[10] += v2.z * cv; acc[11] += v2.w * cv;
        }
        float* g = G1p + (((size_t)(ch * LAYERS + l) * Bn + b) * NCQ + cq) * (LH * Nn);
        if (pad) g[0 * Nn + n] = 0.f;  // high channel t0=0 zero plane (per-cq partial)
#pragma unroll
        for (int t = 0; t < 12; ++t) g[(t + pad) * Nn + n] = acc[t];
    } else {
        // ---- G2 part ----
        int idx = (blk - NBA) * 256 + tid;
        int t0 = idx % LH;
        int c = (idx / LH) % Cc;
        int b = (idx / (LH * Cc)) % Bn;
        int ch = idx / (LH * Cc * Bn);
        const float* X = ch ? XH : XL;
        const float* c2 = ch ? hc2 : lc2;
        int T = ch ? LH : Ll;
        int pad = ch ? 1 : 0;
        for (int j = tid; j < LAYERS * Nn; j += 256) s_c2[j] = c2[j];
        __syncthreads();
        if (t0 >= T) return;
        int tsrc = t0 - pad;
        float a0 = 0.f, a1 = 0.f, a2 = 0.f, a3 = 0.f;
        if (tsrc >= 0) {
            const float* p = X + ((size_t)(b * Cc + c) * Nn) * Ll + tsrc;
            for (int n = 0; n < Nn; ++n) {
                float vx = p[(size_t)n * Ll];
                a0 += vx * s_c2[0 * Nn + n];
                a1 += vx * s_c2[1 * Nn + n];
                a2 += vx * s_c2[2 * Nn + n];
                a3 += vx * s_c2[3 * Nn + n];
            }
        }
        size_t lstride = (size_t)Bn * LH * Cc;
        size_t base = ((size_t)(ch * LAYERS * Bn + b)) * (LH * Cc) + (size_t)t0 * Cc + c;
        G2[base] = a0;
        G2[base + lstride] = a1;
        G2[base + 2 * lstride] = a2;
        G2[base + 3 * lstride] = a3;
    }
}

// ---- per (ch,l,b): GW = G1*w, then M[t0][t1] = sum_c GW*G2 -> global ----
__global__ __launch_bounds__(256) void k_gwm(const float* __restrict__ lw,
                                             const float* __restrict__ hw,
                                             const float* __restrict__ G1p,
                                             const float* __restrict__ G2,
                                             float* __restrict__ M) {
    __shared__ float sG1[LH * Nn];
    __shared__ float sAcc[2][LH * SCW];
    __shared__ float sG2[LH * SCW];
    int blk = blockIdx.x;  // (ch*LAYERS + l)*Bn + b
    int cl = blk / Bn;
    int l = cl % LAYERS;
    int ch = cl / LAYERS;
    int T = ch ? LH : Ll;
    const float* w = (ch ? hw : lw) + (size_t)l * Nn * Cc;
    const float* g1 = G1p + (size_t)blk * (NCQ * LH * Nn);
    const float* g2 = G2 + (size_t)blk * (LH * Cc);
    int tid = threadIdx.x;
    for (int i = tid; i < LH * Nn; i += 256) {
        float a = 0.f;
        if (i < T * Nn) {
#pragma unroll
            for (int cq = 0; cq < NCQ; ++cq) a += g1[(size_t)cq * LH * Nn + i];
        }
        sG1[i] = a;
    }
    for (int i = tid; i < T * Cc; i += 256) sG2[(i / Cc) * SCW + (i % Cc)] = g2[i];
    __syncthreads();
    int half = tid >> 7;
    int c = tid & 127;
    float acc[LH];
#pragma unroll
    for (int t = 0; t < LH; ++t) acc[t] = 0.f;
    int n0 = half ? (Nn / 2) : 0;
    int n1 = half ? Nn : (Nn / 2);
    for (int n = n0; n < n1; ++n) {
        float wv = w[(size_t)n * Cc + c];
#pragma unroll
        for (int t = 0; t < LH; ++t) acc[t] += sG1[t * Nn + n] * wv;
    }
#pragma unroll
    for (int t = 0; t < LH; ++t) sAcc[half][t * SCW + c] = acc[t];
    __syncthreads();
    for (int i = tid; i < LH * Cc; i += 256) {
        int t = i / Cc, cc = i % Cc;
        sAcc[0][t * SCW + cc] += sAcc[1][t * SCW + cc];
    }
    __syncthreads();
    float* Mo = M + (size_t)blk * (LH * LH);
    for (int i = tid; i < T * T; i += 256) {
        int t0 = i / T, t1 = i % T;
        float a = 0.f;
#pragma unroll
        for (int cc = 0; cc < Cc; ++cc) a += sAcc[0][t0 * SCW + cc] * sG2[t1 * SCW + cc];
        Mo[t0 * LH + t1] = a;
    }
}

// ---- 4-layer chain, compile-time T ----
template <int T>
__device__ __forceinline__ void chain_impl(float* __restrict__ sbuf,
                                           float* __restrict__ sMean,
                                           float* __restrict__ sScale,
                                           float* __restrict__ sShift,
                                           const float* __restrict__ M,
                                           const float* __restrict__ bbp,
                                           const float* __restrict__ vp,
                                           const float* __restrict__ gp,
                                           const float* __restrict__ bep,
                                           float* __restrict__ Pcol, int ch) {
    const int TT = T * T;
    const int BUF = Bn * LH * LH;
    int tid = threadIdx.x;
    int ip = 0, ia = 1, ib = 2;
    for (int i = tid; i < Bn * TT; i += 1024) {
        int r = i % TT;
        sbuf[i] = (r / T == r % T) ? 1.f : 0.f;
    }
    __syncthreads();
    for (int l = 0; l < LAYERS; ++l) {
        float* P = sbuf + ip * BUF;
        float* X1 = sbuf + ia * BUF;
        float* X2 = sbuf + ib * BUF;
        const float* Ml = M + ((size_t)(ch * LAYERS + l) * Bn) * (LH * LH);
        const float* bbl = bbp + l * TT;
        const float* vl = vp + l * TT;
        for (int i = tid; i < Bn * LH * LH; i += 1024) X1[i] = Ml[i];
        __syncthreads();
        for (int i = tid; i < Bn * TT; i += 1024) {
            int b = i / TT, r = i % TT, t = r / T, t1 = r % T;
            const float* Pb = P + b * TT;
            const float* Mb = X1 + b * LH * LH;
            float a = 0.f;
#pragma unroll
            for (int t0 = 0; t0 < T; ++t0) a += Pb[t0 * T + t] * Mb[t0 * LH + t1];
            X2[i] = a;
        }
        __syncthreads();
        for (int i = tid; i < Bn * TT; i += 1024) {
            int b = i / TT, r = i % TT, t = r / T, q = r % T;
            const float* S1b = X2 + b * TT + t * T;
            const float* Pb = P + b * TT;
            float a = bbl[r];
#pragma unroll
            for (int t1 = 0; t1 < T; ++t1) a += S1b[t1] * Pb[t1 * T + q];
            X1[i] = 1.f / (1.f + expf(-a));
        }
        __syncthreads();
        for (int i = tid; i < Bn * TT; i += 1024) {
            int b = i / TT, r = i % TT, t = r / T, q = r % T;
            float a = 0.f;
#pragma unroll
            for (int k = 0; k < T; ++k) a += vl[t * T + k] * X1[b * TT + k * T + q];
            X2[i] = a;
        }
        __syncthreads();
        if (tid < T * Bn) {
            int b = tid % Bn, q = tid / Bn;
            float s = 0.f, ss = 0.f;
#pragma unroll
            for (int t = 0; t < T; ++t) {
                float x = X2[b * TT + t * T + q];
                s += x;
                ss += x * x;
            }
            X1[q * Bn + b] = s;
            X1[T * Bn + q * Bn + b] = ss;
        }
        __syncthreads();
        if (tid < T) {
            float s = 0.f, ss = 0.f;
#pragma unroll 8
            for (int b = 0; b < Bn; ++b) {
                s += X1[tid * Bn + b];
                ss += X1[T * Bn + tid * Bn + b];
            }
            float inv = 1.f / (float)(Bn * T);
            float m = s * inv;
            float var = ss * inv - m * m;
            sMean[tid] = m;
            sScale[tid] = rsqrtf(var + BN_EPS) * gp[l * T + tid];
            sShift[tid] = bep[l * T + tid];
        }
        __syncthreads();
        if (tid < Bn * T) {
            int b = tid / T, t = tid % T;
            float vals[T];
            float mx = -1e30f;
#pragma unroll
            for (int q = 0; q < T; ++q) {
                float x = (X2[b * TT + t * T + q] - sMean[q]) * sScale[q] + sShift[q];
                vals[q] = x;
                mx = fmaxf(mx, x);
            }
            float sm = 0.f;
#pragma unroll
            for (int q = 0; q < T; ++q) {
                vals[q] = expf(vals[q] - mx);
                sm += vals[q];
            }
            float inv = 1.f / sm;
#pragma unroll
            for (int q = 0; q < T; ++q) X1[b * TT + t * T + q] = vals[q] * inv;
        }
        __syncthreads();
        for (int i = tid; i < Bn * TT; i += 1024) {
            int b = i / TT, r = i % TT, t0 = r / T, q = r % T;
            const float* Pb = P + b * TT;
            const float* Cb = X1 + b * TT + q * T;
            float a = 0.f;
#pragma unroll
            for (int t = 0; t < T; ++t) a += Pb[t0 * T + t] * Cb[t];
            X2[i] = a;
        }
        __syncthreads();
        int tmp = ip; ip = ib; ib = tmp;
    }
    const float* Pf = sbuf + ip * BUF;
    for (int i = tid; i < Bn * T; i += 1024) {
        int b = i / T, t0 = i % T;
        Pcol[ch * Bn * LH + b * LH + t0] = Pf[b * TT + t0 * T + (T - 1)];
    }
}

__global__ __launch_bounds__(1024) void k_chain(const float* __restrict__ M,
                                                const float* __restrict__ lb,
                                                const float* __restrict__ lv,
                                                const float* __restrict__ lg,
                                                const float* __restrict__ lbe,
                                                const float* __restrict__ hb,
                                                const float* __restrict__ hv,
                                                const float* __restrict__ hg,
                                                const float* __restrict__ hbe,
                                                float* __restrict__ Pcol) {
    __shared__ float sbuf[3 * Bn * LH * LH];
    __shared__ float sMean[LH], sScale[LH], sShift[LH];
    int ch = blockIdx.x;
    if (ch == 0)
        chain_impl<Ll>(sbuf, sMean, sScale, sShift, M, lb, lv, lg, lbe, Pcol, 0);
    else
        chain_impl<LH>(sbuf, sMean, sScale, sShift, M, hb, hv, hg, hbe, Pcol, 1);
}

// ---- final: residuals + alpha blend, float4 loads ----
__global__ __launch_bounds__(256) void k_final(const float* __restrict__ XL,
                                               const float* __restrict__ XH,
                                               const float* __restrict__ Pcol,
                                               const float* __restrict__ alpha,
                                               float* __restrict__ out) {
    __shared__ float s_pl[Ll];
    __shared__ float s_ph[LH];
    int b = blockIdx.y;
    int tid = threadIdx.x;
    if (tid < Ll) s_pl[tid] = Pcol[b * LH + tid];
    if (tid < LH) s_ph[tid] = Pcol[Bn * LH + b * LH + tid];
    __syncthreads();
    int cn = blockIdx.x * blockDim.x + tid;
    if (cn >= Cc * Nn) return;
    size_t idx = (size_t)b * Cc * Nn + cn;
    const float4* pl4 = (const float4*)(XL + idx * Ll);
    const float4* ph4 = (const float4*)(XH + idx * Ll);
    float4 l0 = pl4[0], l1 = pl4[1], l2 = pl4[2];
    float4 h0 = ph4[0], h1 = ph4[1], h2 = ph4[2];
    float accL = l0.x * s_pl[0] + l0.y * s_pl[1] + l0.z * s_pl[2] + l0.w * s_pl[3]
               + l1.x * s_pl[4] + l1.y * s_pl[5] + l1.z * s_pl[6] + l1.w * s_pl[7]
               + l2.x * s_pl[8] + l2.y * s_pl[9] + l2.z * s_pl[10] + l2.w * s_pl[11];
    float accH = h0.x * s_ph[1] + h0.y * s_ph[2] + h0.z * s_ph[3] + h0.w * s_ph[4]
               + h1.x * s_ph[5] + h1.y * s_ph[6] + h1.z * s_ph[7] + h1.w * s_ph[8]
               + h2.x * s_ph[9] + h2.y * s_ph[10] + h2.z * s_ph[11] + h2.w * s_ph[12];
    float a = 1.f / (1.f + expf(-alpha[0]));
    float xl = l2.w + accL;
    float xh = h2.w + accH;
    out[idx] = a * xl + (1.f - a) * xh;
}

extern "C" void kernel_launch(void* const* d_in, const int* in_sizes, int n_in,
                              void* d_out, int out_size, void* d_ws, size_t ws_size,
                              hipStream_t stream) {
    const float* XL = (const float*)d_in[0];
    const float* XH = (const float*)d_in[1];
    const float* lc1 = (const float*)d_in[2];
    const float* lc2 = (const float*)d_in[3];
    const float* lw = (const float*)d_in[4];
    const float* lb = (const float*)d_in[5];
    const float* lv = (const float*)d_in[6];
    const float* lg = (const float*)d_in[7];
    const float* lbeta = (const float*)d_in[8];
    const float* hc1 = (const float*)d_in[9];
    const float* hc2 = (const float*)d_in[10];
    const float* hw = (const float*)d_in[11];
    const float* hb = (const float*)d_in[12];
    const float* hv = (const float*)d_in[13];
    const float* hg = (const float*)d_in[14];
    const float* hbeta = (const float*)d_in[15];
    const float* alpha = (const float*)d_in[16];
    float* out = (float*)d_out;

    float* ws = (float*)d_ws;
    float* G1p = ws;                                                  // 256*4*13*307 = 4.08M floats
    float* G2 = G1p + (size_t)2 * LAYERS * Bn * NCQ * LH * Nn;        // 425,984
    float* M = G2 + (size_t)2 * LAYERS * Bn * LH * Cc;                // 43,264
    float* Pcol = M + (size_t)2 * LAYERS * Bn * LH * LH;              // 832
    // total ~18.5 MB

    k_g12<<<NBA + NBB, 256, 0, stream>>>(XL, XH, lc1, hc1, lc2, hc2, G1p, G2);
    k_gwm<<<2 * LAYERS * Bn, 256, 0, stream>>>(lw, hw, G1p, G2, M);
    k_chain<<<2, 1024, 0, stream>>>(M, lb, lv, lg, lbeta, hb, hv, hg, hbeta, Pcol);
    k_final<<<dim3((Cc * Nn + 255) / 256, Bn), 256, 0, stream>>>(XL, XH, Pcol, alpha, out);
}